// Round 1
// baseline (243.567 us; speedup 1.0000x reference)
//
#include <hip/hip_runtime.h>
#include <math.h>

#define NB 8
#define NC 256
#define NHW 2304
#define NG 32
#define CPG 8
#define GN_EPS 1e-5f
#define ATT_SCALE 0.0625f
#define XSTR 258   // k_xnT transpose LDS stride (bf16)

typedef __bf16 bf16x8 __attribute__((ext_vector_type(8)));
typedef __bf16 bf16x4 __attribute__((ext_vector_type(4)));
typedef float f32x4 __attribute__((ext_vector_type(4)));

#define MFMA(a, b, c) __builtin_amdgcn_mfma_f32_16x16x32_bf16(a, b, c, 0, 0, 0)

__device__ __forceinline__ void async_lds16(const void* g, void* l) {
  __builtin_amdgcn_global_load_lds(
      (const __attribute__((address_space(1))) void*)g,
      (__attribute__((address_space(3))) void*)l, 16, 0, 0);
}

// ---------------------------------------------------------------------------
// Kernel 1: merged GN-stats (blocks 0..255) + W fp32->bf16 cast (256..447).
// ---------------------------------------------------------------------------
__global__ __launch_bounds__(256) void k_prep(
    const float* __restrict__ x, const float* __restrict__ gn_w,
    const float* __restrict__ gn_b, float* __restrict__ scale,
    float* __restrict__ shift,
    const float* __restrict__ Wq, const float* __restrict__ Wk,
    const float* __restrict__ Wv, __bf16* __restrict__ Wqb,
    __bf16* __restrict__ Wkb, __bf16* __restrict__ Wvb) {
  __shared__ float red[8];
  int blk = blockIdx.x;
  if (blk >= 256) {  // ---- weight cast ----
    int idx = blk - 256;
    int which = idx >> 6;
    const float* src = which == 0 ? Wq : (which == 1 ? Wk : Wv);
    __bf16* dst = which == 0 ? Wqb : (which == 1 ? Wkb : Wvb);
    int i = (idx & 63) * 256 + threadIdx.x;
    float4 v = ((const float4*)src)[i];
    bf16x4 o;
    o[0] = (__bf16)v.x; o[1] = (__bf16)v.y;
    o[2] = (__bf16)v.z; o[3] = (__bf16)v.w;
    ((bf16x4*)dst)[i] = o;
    return;
  }
  // ---- GroupNorm stats ----
  const float4* base = (const float4*)(x + (size_t)blk * CPG * NHW);
  const int n4 = CPG * NHW / 4;
  float s = 0.f, ss = 0.f;
  for (int i = threadIdx.x; i < n4; i += 256) {
    float4 v = base[i];
    s  += v.x + v.y + v.z + v.w;
    ss += v.x * v.x + v.y * v.y + v.z * v.z + v.w * v.w;
  }
  for (int off = 32; off > 0; off >>= 1) {
    s  += __shfl_down(s, off);
    ss += __shfl_down(ss, off);
  }
  int wv = threadIdx.x >> 6, ln = threadIdx.x & 63;
  if (ln == 0) { red[wv] = s; red[4 + wv] = ss; }
  __syncthreads();
  if (threadIdx.x < CPG) {
    float S  = red[0] + red[1] + red[2] + red[3];
    float SS = red[4] + red[5] + red[6] + red[7];
    const float inv_n = 1.f / (float)(CPG * NHW);
    float mean = S * inv_n;
    float var  = SS * inv_n - mean * mean;
    float rstd = rsqrtf(var + GN_EPS);
    int b = blk / NG, g = blk % NG;
    int c = g * CPG + threadIdx.x;
    float sc = gn_w[c] * rstd;
    scale[b * NC + c] = sc;
    shift[b * NC + c] = gn_b[c] - mean * sc;
  }
}

// ---------------------------------------------------------------------------
// Kernel 2: normalize + transpose x[c][p] fp32 -> xnT[p][c] bf16 via LDS.
// ---------------------------------------------------------------------------
__global__ __launch_bounds__(256) void k_xnT(
    const float* __restrict__ x, const float* __restrict__ scale,
    const float* __restrict__ shift, __bf16* __restrict__ xnT) {
  __shared__ __bf16 t[64 * XSTR];
  int p0 = blockIdx.x * 64;
  int b = blockIdx.y;
  int w = threadIdx.x >> 6, lane = threadIdx.x & 63;
  const float* xb = x + (size_t)b * NC * NHW;
  const float* scb = scale + b * NC;
  const float* shb = shift + b * NC;
#pragma unroll 8
  for (int i = 0; i < 64; ++i) {
    int c = i * 4 + w;
    float v = xb[(size_t)c * NHW + p0 + lane] * scb[c] + shb[c];
    t[lane * XSTR + c] = (__bf16)v;
  }
  __syncthreads();
#pragma unroll
  for (int i = 0; i < 8; ++i) {
    int row = i * 8 + w * 2 + (lane >> 5);
    int c8 = (lane & 31) * 8;
    bf16x8 v8 = *(const bf16x8*)&t[row * XSTR + c8];
    *(bf16x8*)&xnT[((size_t)b * NHW + p0 + row) * NC + c8] = v8;
  }
}

// ---------------------------------------------------------------------------
// Kernel 3: QKV GEMM. Block: 128p x 64o, 4 waves m-split (32p each).
// One xf fragment set feeds all three GEMMs; LDS-transposed coalesced stores.
// grid: 18pg x 4oq x 8b = 576; b = blk&7 (XCD locality).
// ---------------------------------------------------------------------------
__global__ __launch_bounds__(256) void k_qkv(
    const __bf16* __restrict__ xnT,
    const __bf16* __restrict__ Wqb, const __bf16* __restrict__ Wkb,
    const __bf16* __restrict__ Wvb,
    const float* __restrict__ bq, const float* __restrict__ bk,
    const float* __restrict__ bv,
    __bf16* __restrict__ qT, __bf16* __restrict__ kT,
    __bf16* __restrict__ vbuf) {
  __shared__ __bf16 tile[9216];  // q/k: [128][72]; v: [64][136]
  int blk = blockIdx.x;
  int b = blk & 7;
  int r = blk >> 3;
  int oq = r & 3;
  int pg = r >> 2;
  int p0 = pg * 128, o0 = oq * 64;
  int tid = threadIdx.x;
  int w = tid >> 6, lane = tid & 63;
  int col = lane & 15, quad = lane >> 4;

  const __bf16* xrow =
      xnT + ((size_t)b * NHW + p0 + w * 32 + col) * NC + quad * 8;
  bf16x8 xf[2][8];
#pragma unroll
  for (int mt = 0; mt < 2; ++mt)
#pragma unroll
    for (int ks = 0; ks < 8; ++ks)
      xf[mt][ks] = *(const bf16x8*)(xrow + (size_t)mt * 16 * NC + ks * 32);

#pragma unroll
  for (int t = 0; t < 3; ++t) {
    const __bf16* W = t == 0 ? Wqb : (t == 1 ? Wkb : Wvb);
    const float* bias = t == 0 ? bq : (t == 1 ? bk : bv);
    f32x4 acc[2][4];
#pragma unroll
    for (int mt = 0; mt < 2; ++mt)
#pragma unroll
      for (int nt = 0; nt < 4; ++nt) acc[mt][nt] = (f32x4){0.f, 0.f, 0.f, 0.f};
#pragma unroll
    for (int nt = 0; nt < 4; ++nt) {
      const __bf16* wrow = W + ((size_t)(o0 + nt * 16 + col)) * NC + quad * 8;
#pragma unroll
      for (int ks = 0; ks < 8; ++ks) {
        bf16x8 wf = *(const bf16x8*)(wrow + ks * 32);
        acc[0][nt] = MFMA(xf[0][ks], wf, acc[0][nt]);
        acc[1][nt] = MFMA(xf[1][ks], wf, acc[1][nt]);
      }
    }
    if (t > 0) __syncthreads();  // previous tile reads done
    if (t < 2) {
      // stage D[p][o] + bias -> tile[128][72]
#pragma unroll
      for (int mt = 0; mt < 2; ++mt)
#pragma unroll
        for (int nt = 0; nt < 4; ++nt) {
          float bc = bias[o0 + nt * 16 + col];
#pragma unroll
          for (int reg = 0; reg < 4; ++reg) {
            int row = w * 32 + mt * 16 + quad * 4 + reg;
            tile[row * 72 + nt * 16 + col] = (__bf16)(acc[mt][nt][reg] + bc);
          }
        }
      __syncthreads();
      __bf16* dst = t == 0 ? qT : kT;
#pragma unroll
      for (int pass = 0; pass < 4; ++pass) {
        int unit = pass * 256 + tid;
        int row = unit >> 3, ch = unit & 7;
        bf16x8 v8 = *(const bf16x8*)&tile[row * 72 + ch * 8];
        *(bf16x8*)&dst[((size_t)b * NHW + p0 + row) * NC + o0 + ch * 8] = v8;
      }
    } else {
      // V: stage transposed [o][p] -> tile[64][136]
#pragma unroll
      for (int mt = 0; mt < 2; ++mt)
#pragma unroll
        for (int nt = 0; nt < 4; ++nt) {
          float bc = bias[o0 + nt * 16 + col];
#pragma unroll
          for (int reg = 0; reg < 4; ++reg) {
            int p = w * 32 + mt * 16 + quad * 4 + reg;
            tile[(nt * 16 + col) * 136 + p] = (__bf16)(acc[mt][nt][reg] + bc);
          }
        }
      __syncthreads();
#pragma unroll
      for (int pass = 0; pass < 4; ++pass) {
        int unit = pass * 256 + tid;
        int row = unit >> 4, ch = unit & 15;  // row = o-local, ch = 16B p-chunk
        bf16x8 v8 = *(const bf16x8*)&tile[row * 136 + ch * 8];
        *(bf16x8*)&vbuf[((size_t)b * NC + o0 + row) * NHW + p0 + ch * 8] = v8;
      }
    }
  }
}

// ---------------------------------------------------------------------------
// Kernel 4: FUSED flash attention. One block = (batch b, 64-q tile).
// Loop over 36 k-tiles of 64:
//   stage K[64][256] + V[256][64] (global_load_lds, XOR-chunk swizzle)
//   S^T = K . Q^T  (Q held in regs; 4 waves = 2 k-halves x 2 q-halves)
//   P = exp(S/16) -> packed bf16 into swizzled LDS tile [64q][64k]
//   lsum accumulated in registers (shfl reduce, no atomics)
//   acc[c][q] += V . P^T (V m-split per wave: no LDS duplication)
// Epilogue: cross-wave lsum combine in LDS, normalize, store fp32 out.
// grid 36qg x 8b = 288, 2 blocks/CU (LDS 74 KB, ~210 VGPR).
// ---------------------------------------------------------------------------
__global__ __launch_bounds__(256, 2) void k_fused(
    const __bf16* __restrict__ qT, const __bf16* __restrict__ kT,
    const __bf16* __restrict__ vbuf, float* __restrict__ out) {
  __shared__ __bf16 sk[64 * 256];   // K tile [64k][256c], swizzled, 32 KB
  __shared__ __bf16 sv[256 * 64];   // V tile [256c][64k], swizzled, 32 KB
  __shared__ __bf16 sp[64 * 64];    // P tile [64q][64k],  swizzled,  8 KB
  __shared__ float slsum[2][64];

  int blk = blockIdx.x;
  int b = blk & 7;          // XCD locality: batch b -> XCD b
  int qg = blk >> 3;
  int q0 = qg * 64;
  int tid = threadIdx.x;
  int w = tid >> 6, lane = tid & 63;
  int wm = w >> 1, wn = w & 1;      // 2 k-halves x 2 q-halves for S^T
  int col = lane & 15, quad = lane >> 4;
  int c7 = col & 7;

  // ---- staging (wave w: K rows w*16..+16, V rows w*64..+64) ----
  auto stage_kv = [&](int it2) {
    int k0 = it2 * 64;
    {
      int sub = lane >> 5, p5 = lane & 31;
#pragma unroll
      for (int j = 0; j < 8; ++j) {
        int r0 = w * 16 + j * 2;
        int rloc = r0 + sub;
        int g = p5 ^ (rloc & 7);
        async_lds16(kT + ((size_t)b * NHW + k0 + rloc) * NC + g * 8,
                    (void*)&sk[r0 * 256]);
      }
    }
    {
      int sub = lane >> 3, p3 = lane & 7;
#pragma unroll
      for (int j = 0; j < 8; ++j) {
        int r0 = w * 64 + j * 8;
        int rloc = r0 + sub;
        int g = p3 ^ (rloc & 7);
        async_lds16(vbuf + ((size_t)b * NC + rloc) * NHW + k0 + g * 8,
                    (void*)&sv[r0 * 64]);
      }
    }
  };

  // ---- Q fragments: held in registers for all 36 iterations ----
  // wave (wm,wn): q rows wn*32 + nt*16 + col, nt = 0..1
  const __bf16* qrow =
      qT + ((size_t)b * NHW + q0 + wn * 32 + col) * NC + quad * 8;
  bf16x8 qf[2][8];
#pragma unroll
  for (int nt = 0; nt < 2; ++nt)
#pragma unroll
    for (int ks = 0; ks < 8; ++ks)
      qf[nt][ks] = *(const bf16x8*)(qrow + (size_t)nt * 16 * NC + ks * 32);

  stage_kv(0);

  f32x4 acc[4][4];
#pragma unroll
  for (int mt = 0; mt < 4; ++mt)
#pragma unroll
    for (int nt = 0; nt < 4; ++nt) acc[mt][nt] = (f32x4){0.f, 0.f, 0.f, 0.f};
  float lsum_r[2] = {0.f, 0.f};

  for (int it = 0; it < 36; ++it) {
    __syncthreads();  // B1: stages landed (vmcnt0), prev P/V reads drained

    // ---- S^T[k][q] = sum_c K[k][c] * Q[q][c] ----
    f32x4 sacc[2][2];
#pragma unroll
    for (int mt = 0; mt < 2; ++mt)
#pragma unroll
      for (int nt = 0; nt < 2; ++nt) sacc[mt][nt] = (f32x4){0.f, 0.f, 0.f, 0.f};
#pragma unroll
    for (int ks = 0; ks < 8; ++ks) {
#pragma unroll
      for (int mt = 0; mt < 2; ++mt) {
        int krow = wm * 32 + mt * 16 + col;
        bf16x8 kf = *(const bf16x8*)
            &sk[krow * 256 + (((ks * 4 + quad) ^ c7) << 3)];
        sacc[mt][0] = MFMA(kf, qf[0][ks], sacc[mt][0]);
        sacc[mt][1] = MFMA(kf, qf[1][ks], sacc[mt][1]);
      }
    }

    // ---- exp, running row-sum, pack P -> swizzled LDS ----
#pragma unroll
    for (int nt = 0; nt < 2; ++nt) {
      float ps = 0.f;
      int q = wn * 32 + nt * 16 + col;
#pragma unroll
      for (int mt = 0; mt < 2; ++mt) {
        bf16x4 pk;
#pragma unroll
        for (int reg = 0; reg < 4; ++reg) {
          float e = __expf(sacc[mt][nt][reg] * ATT_SCALE);
          ps += e;
          pk[reg] = (__bf16)e;
        }
        // logical k = wm*32 + mt*16 + quad*4; chunk swizzle ^ (q&7) (== c7)
        int chunk = (wm * 4 + mt * 2 + (quad >> 1)) ^ c7;
        *(bf16x4*)&sp[q * 64 + chunk * 8 + (quad & 1) * 4] = pk;
      }
      ps += __shfl_xor(ps, 16);
      ps += __shfl_xor(ps, 32);   // now all quads hold this wave's 32-k sum
      lsum_r[nt] += ps;
    }

    __syncthreads();  // B2: P visible; all waves' K reads drained

    // ---- load P B-frags (all 64 q) and V A-frags (wave's 64 c) to regs ----
    bf16x8 pf[4][2], vf[4][2];
#pragma unroll
    for (int nt = 0; nt < 4; ++nt) {
      int q = nt * 16 + col;
#pragma unroll
      for (int ks = 0; ks < 2; ++ks)
        pf[nt][ks] = *(const bf16x8*)
            &sp[q * 64 + (((ks * 4 + quad) ^ c7) << 3)];
    }
#pragma unroll
    for (int mt = 0; mt < 4; ++mt) {
      int crow = w * 64 + mt * 16 + col;
#pragma unroll
      for (int ks = 0; ks < 2; ++ks)
        vf[mt][ks] = *(const bf16x8*)
            &sv[crow * 64 + (((ks * 4 + quad) ^ c7) << 3)];
    }
    if (it < 35) {
      // all of this wave's K/V/P reads must be complete before restage
      asm volatile("s_waitcnt lgkmcnt(0)" ::: "memory");
      __builtin_amdgcn_sched_barrier(0);
      stage_kv(it + 1);  // in flight across PV + next B1
    }

    // ---- acc[c][q] += V . P^T ----
#pragma unroll
    for (int mt = 0; mt < 4; ++mt)
#pragma unroll
      for (int nt = 0; nt < 4; ++nt) {
        acc[mt][nt] = MFMA(vf[mt][0], pf[nt][0], acc[mt][nt]);
        acc[mt][nt] = MFMA(vf[mt][1], pf[nt][1], acc[mt][nt]);
      }
  }

  // ---- cross-wave lsum combine ----
  if (quad == 0) {
#pragma unroll
    for (int nt = 0; nt < 2; ++nt)
      slsum[wm][wn * 32 + nt * 16 + col] = lsum_r[nt];
  }
  __syncthreads();

  // ---- normalize + store ----
  float* ob = out + (size_t)b * NC * NHW;
#pragma unroll
  for (int nt = 0; nt < 4; ++nt) {
    int q = nt * 16 + col;
    float inv = 1.f / (slsum[0][q] + slsum[1][q]);
#pragma unroll
    for (int mt = 0; mt < 4; ++mt) {
#pragma unroll
      for (int reg = 0; reg < 4; ++reg) {
        int c = w * 64 + mt * 16 + quad * 4 + reg;
        ob[(size_t)c * NHW + q0 + q] = acc[mt][nt][reg] * inv;
      }
    }
  }
}

// ---------------------------------------------------------------------------
extern "C" void kernel_launch(void* const* d_in, const int* in_sizes, int n_in,
                              void* d_out, int out_size, void* d_ws,
                              size_t ws_size, hipStream_t stream) {
  const float* x   = (const float*)d_in[0];
  const float* Wq  = (const float*)d_in[1];
  const float* bq  = (const float*)d_in[2];
  const float* Wk  = (const float*)d_in[3];
  const float* bk  = (const float*)d_in[4];
  const float* Wv  = (const float*)d_in[5];
  const float* bv  = (const float*)d_in[6];
  const float* gnw = (const float*)d_in[7];
  const float* gnb = (const float*)d_in[8];
  float* out = (float*)d_out;

  const size_t per = (size_t)NB * NC * NHW;          // 4,718,592 elems
  const size_t psz = (size_t)NB * NHW * NHW * 2;     // (old P region, unused)
  char* wsb = (char*)d_ws;
  __bf16* qT   = (__bf16*)wsb;
  __bf16* kT   = (__bf16*)(wsb + per * 2);
  __bf16* vbuf = (__bf16*)(wsb + per * 4);
  __bf16* xnT  = (__bf16*)(wsb + per * 6);  // dead after k_qkv
  char* tail   = wsb + per * 6 + psz;
  __bf16* Wqb  = (__bf16*)tail;
  __bf16* Wkb  = Wqb + NC * NC;
  __bf16* Wvb  = Wkb + NC * NC;
  float* scale = (float*)(Wvb + NC * NC);
  float* shift = scale + NB * NC;

  hipLaunchKernelGGL(k_prep, dim3(448), dim3(256), 0, stream,
                     x, gnw, gnb, scale, shift, Wq, Wk, Wv, Wqb, Wkb, Wvb);
  hipLaunchKernelGGL(k_xnT, dim3(NHW / 64, NB), dim3(256), 0, stream,
                     x, scale, shift, xnT);
  hipLaunchKernelGGL(k_qkv, dim3(576), dim3(256), 0, stream,
                     xnT, Wqb, Wkb, Wvb, bq, bk, bv, qT, kT, vbuf);
  hipLaunchKernelGGL(k_fused, dim3(288), dim3(256), 0, stream,
                     qT, kT, vbuf, out);
}